// Round 7
// baseline (542.036 us; speedup 1.0000x reference)
//
#include <hip/hip_runtime.h>

// Soft-DTW, gamma=1.0, B=64, N=M=1024, log2-domain DP, barrier-free.
// Pair-representation inside each 4x4 tile (u,s), normalized at tile
// boundaries (v = u - log2(s)); numerics identical to R5/R6 (absmax 0.0).
//
// Structure: one 256-thread block per batch, 4 waves. Lane l of wave w owns
// DP rows (64w+l)*4 .. +3. Wave-internal software pipeline: at iteration j,
// lane l computes chunk c = j - l (CW=4 columns). Top boundary comes from
// lane l-1 via __shfl_up (lockstep, no sync). Cross-wave boundary (3x) via
// full-ring LDS mailbox (256 slots, written once) + monotone seq counter:
// producer lane63 writes payload, lgkmcnt(0), writes seq; consumer lane0
// polls seq >= c, then reads payload. NO s_barrier in the main loop.
//
// D loads: inline-asm global_load_dwordx4 (compiler cannot sink them),
// unconditional with clamped chunk index -> exactly 16 dwords/iteration ->
// exact counted s_waitcnt vmcnt(8) (2 batches in flight, never drain to 0),
// followed by sched_barrier(0) so compute can't hoist above the wait.

#define BIGV 1.0e10f
#define LOG2E 1.4426950408889634f
#define LN2 0.6931471805599453f

constexpr int N = 1024;
constexpr int TPB = 256;
constexpr int NW = 4;              // waves per block
constexpr int R = 4;               // rows per thread
constexpr int CW = 4;              // columns per chunk
constexpr int K = N / CW;          // 256 chunks per lane
constexpr int ITER = 64 + K;       // 320 iterations (319 real + 1 pad)

__device__ __forceinline__ float fexp2(float x) {
    float r; asm("v_exp_f32 %0, %1" : "=v"(r) : "v"(x)); return r;
}
__device__ __forceinline__ float flog2(float x) {
    float r; asm("v_log_f32 %0, %1" : "=v"(r) : "v"(x)); return r;
}
__device__ __forceinline__ float fmin3(float a, float b, float c) {
    float r; asm("v_min3_f32 %0, %1, %2, %3" : "=v"(r) : "v"(a), "v"(b), "v"(c));
    return r;
}
__device__ __forceinline__ void gload4(float4& d, const float* p) {
    asm volatile("global_load_dwordx4 %0, %1, off" : "=v"(d) : "v"(p));
}
__device__ __forceinline__ float f4get(const float4& v, int m) {
    return m == 0 ? v.x : m == 1 ? v.y : m == 2 ? v.z : v.w;
}

__global__ __launch_bounds__(TPB)
void softdtw_kernel(const float* __restrict__ D, float* __restrict__ out) {
    const int b = blockIdx.x;
    const int t = threadIdx.x;
    const int lane = t & 63;
    const int w = t >> 6;
    const float* __restrict__ Db = D + (size_t)b * N * N;
    const int i0 = t * R;

    __shared__ float ring[NW - 1][K][CW];
    __shared__ int seqv[NW - 1];

    if (t < NW - 1) seqv[t] = -1;
    __syncthreads();   // once, before the pipeline

    float Lv[R], Bv[CW];
#pragma unroll
    for (int r = 0; r < R; ++r) Lv[r] = BIGV;
#pragma unroll
    for (int m = 0; m < CW; ++m) Bv[m] = BIGV;
    float Cv = (t == 0) ? 0.0f : BIGV;

    float4 dA[R], dB[R], dC[R], dD[R];

    auto ISSUE = [&](float4 (&pf)[R], int j) {
        int cn = j - lane;
        int cc = min(max(cn, 0), K - 1);
        const float* base = Db + (size_t)i0 * N + cc * CW;
#pragma unroll
        for (int r = 0; r < R; ++r) gload4(pf[r], base + (size_t)r * N);
    };

    auto STEP = [&](int j, float4 (&cur)[R], float4 (&pf)[R]) {
        ISSUE(pf, j + 2);                     // prefetch depth 2

        // top boundary from lane-1 (previous iteration's bottom row)
        float T1 = __shfl_up(Bv[0], 1);
        float T2 = __shfl_up(Bv[1], 1);
        float T3 = __shfl_up(Bv[2], 1);
        float T4 = __shfl_up(Bv[3], 1);

        const int c = j - lane;
        const bool active = (c >= 0) && (c < K);

        if (lane == 0) {
            if (w == 0) {
                T1 = T2 = T3 = T4 = BIGV;     // DP row 0 padding
            } else if (active) {
                volatile int* sp = &seqv[w - 1];
                int sv;
                do { sv = *sp; } while (sv < c);
                asm volatile("" ::: "memory");
                volatile float* rp = &ring[w - 1][c][0];
                T1 = rp[0]; T2 = rp[1]; T3 = rp[2]; T4 = rp[3];
            }
        }

        // D(chunk j) was issued 2 iterations ago; 2 batches (8 loads) after it
        asm volatile("s_waitcnt vmcnt(8)" ::: "memory");
        __builtin_amdgcn_sched_barrier(0);

        if (active) {
            float Tv[CW + 1] = {Cv, T1, T2, T3, T4};
            Cv = Tv[CW];

            float Vu[R][CW], Vs[R][CW];
#pragma unroll
            for (int l = 0; l < R + CW - 1; ++l) {
#pragma unroll
                for (int r = 0; r < R; ++r) {
                    const int m = l - r;
                    if (m >= 0 && m < CW) {
                        const bool aOne = (r == 0) || (m == 0);
                        const bool bOne = (r == 0);
                        const bool cOne = (m == 0);
                        float ua = (r == 0) ? Tv[m]
                                 : ((m == 0) ? Lv[r - 1] : Vu[r - 1][m - 1]);
                        float sa = aOne ? 1.0f : Vs[r - 1][m - 1];
                        float ub = (r == 0) ? Tv[m + 1] : Vu[r - 1][m];
                        float sb = bOne ? 1.0f : Vs[r - 1][m];
                        float uc = (m == 0) ? Lv[r] : Vu[r][m - 1];
                        float sc = cOne ? 1.0f : Vs[r][m - 1];

                        float mn = fmin3(ua, ub, uc);
                        float ea = fexp2(mn - ua);
                        float eb = fexp2(mn - ub);
                        float ec = fexp2(mn - uc);
                        float sig = aOne ? ea : sa * ea;
                        sig = bOne ? (sig + eb) : fmaf(sb, eb, sig);
                        sig = cOne ? (sig + ec) : fmaf(sc, ec, sig);
                        float un = fmaf(f4get(cur[r], m), LOG2E, mn);
                        Vu[r][m] = un;
                        Vs[r][m] = sig;

                        if (r == R - 1 || m == CW - 1) {
                            float vn = un - flog2(sig);
                            if (r == R - 1) Bv[m] = vn;
                            if (m == CW - 1) Lv[r] = vn;
                        }
                    }
                }
            }

            if (lane == 63 && w < NW - 1) {
                volatile float* rp = &ring[w][c][0];
                rp[0] = Bv[0]; rp[1] = Bv[1]; rp[2] = Bv[2]; rp[3] = Bv[3];
                asm volatile("s_waitcnt lgkmcnt(0)" ::: "memory");
                *(volatile int*)&seqv[w] = c;
            }
        }
    };

    ISSUE(dA, 0);
    ISSUE(dB, 1);
    for (int j = 0; j < ITER; j += 4) {
        STEP(j,     dA, dC);
        STEP(j + 1, dB, dD);
        STEP(j + 2, dC, dA);
        STEP(j + 3, dD, dB);
    }

    // R[N][N] = thread 255's Lv[3] (normalized); unscale from log2 domain
    if (t == TPB - 1) out[b] = Lv[R - 1] * LN2;
}

extern "C" void kernel_launch(void* const* d_in, const int* in_sizes, int n_in,
                              void* d_out, int out_size, void* d_ws, size_t ws_size,
                              hipStream_t stream) {
    const float* D = (const float*)d_in[0];
    float* out = (float*)d_out;
    const int B = in_sizes[0] / (N * N);
    softdtw_kernel<<<B, TPB, 0, stream>>>(D, out);
}

// Round 8
// 339.968 us; speedup vs baseline: 1.5944x; 1.5944x over previous
//
#include <hip/hip_runtime.h>

// Soft-DTW, gamma=1.0, B=64, N=M=1024, log2-domain DP.
// Column-strip row-sweep wavefront: one 256-thread block per batch.
// Thread t owns DP columns 4t+1..4t+4; at iteration j it computes row
// i = j - t + 1 (4 cells). Links = N + TPB - 1 = 1279, each link costs only:
//   2x shfl_up (edge pair from thread t-1), 4-cell pair-softmin chain.
// No barriers. Cross-wave boundaries (3) use an LDS ring mailbox (groups of
// 8 rows, seq counter); consumers read once per 8 iterations.
// Pair representation: cell = (u, s), value v = u - log2(s); renormalized
// every 8 rows (uniform in j) so s stays bounded (<= ~3^12). Only log2s are
// the 4-per-8-rows renorm (off the critical path) + final output.
// D loads: per-thread float4 of its 4 columns, consecutive threads ->
// contiguous 1KB/wave (coalesced). 8-deep asm global_load_dwordx4 ring,
// constant s_waitcnt vmcnt(7) (never drained to 0), sched_barrier after.

#define BIGV 1.0e10f
#define LOG2E 1.4426950408889634f
#define LN2  0.6931471805599453f

constexpr int N = 1024;
constexpr int TPB = 256;
constexpr int CW = 4;                 // columns per thread
constexpr int NWAVE = TPB / 64;       // 4
constexpr int RS = 16;                // ring slots (groups of 8 rows)
constexpr int NG = 160;               // ceil((N + TPB - 1) / 8) = 160 groups

__device__ __forceinline__ float fexp2(float x){float r;asm("v_exp_f32 %0, %1":"=v"(r):"v"(x));return r;}
__device__ __forceinline__ float flog2(float x){float r;asm("v_log_f32 %0, %1":"=v"(r):"v"(x));return r;}
__device__ __forceinline__ float fmin3(float a,float b,float c){float r;asm("v_min3_f32 %0,%1,%2,%3":"=v"(r):"v"(a),"v"(b),"v"(c));return r;}
__device__ __forceinline__ void gload4(float4& d, const float* p){
    asm volatile("global_load_dwordx4 %0, %1, off" : "=v"(d) : "v"(p));
}

__global__ __launch_bounds__(TPB)
void softdtw_kernel(const float* __restrict__ D, float* __restrict__ out){
    const int b = blockIdx.x;
    const int t = threadIdx.x;
    const int lane = t & 63;
    const int w = t >> 6;
    const float* __restrict__ Db = D + (size_t)b * N * N;
    const float* __restrict__ dbase = Db + (size_t)t * CW;   // my 4 columns

    __shared__ float ring[NWAVE-1][RS][8][2];
    __shared__ int seqv[NWAVE-1];
    if (t < NWAVE-1) seqv[t] = -1;
    __syncthreads();                  // once, before the pipeline

    float pu[CW], ps[CW];             // previous-row pairs for my 4 columns
#pragma unroll
    for (int m = 0; m < CW; ++m) { pu[m] = BIGV; ps[m] = 1.0f; }
    float exU = BIGV, exS = 1.0f;     // my exported right-edge pair (row i)
    float leU = (t == 0) ? 0.0f : BIGV, leS = 1.0f;  // left edge (rotates to up-left; t0 corner)
    float luU = BIGV, luS = 1.0f;     // up-left (row i-1 edge)
    float mbU[8], mbS[8];             // mailbox receive buffer (8 rows)
#pragma unroll
    for (int q2 = 0; q2 < 8; ++q2) { mbU[q2] = BIGV; mbS[q2] = 1.0f; }

    float4 buf[8];
    // prologue: issue loads for iterations j=0..7 (data row dr=j-t, clamped)
#pragma unroll
    for (int q2 = 0; q2 < 8; ++q2) {
        int rr = q2 - t; rr = rr < 0 ? 0 : (rr > N - 1 ? N - 1 : rr);
        gload4(buf[q2], dbase + (size_t)rr * N);
    }

    for (int jg = 0; jg < NG; ++jg) {
#pragma unroll
        for (int q = 0; q < 8; ++q) {
            const int j = jg * 8 + q;
            const int dr = j - t;                  // data row = i-1
            const bool active = (unsigned)dr < (unsigned)N;

            // mailbox receive, once per group (lane 0 of waves 1..3)
            if (q == 0) {
                if (lane == 0 && w > 0) {
                    const int gq = dr >> 3;        // = jg - 8w
                    if (gq >= 0 && gq < N / 8) {
                        volatile int* sp = &seqv[w - 1];
                        int sv; do { sv = *sp; } while (sv < gq);
                        asm volatile("s_waitcnt lgkmcnt(0)" ::: "memory");
                        const float* rp = &ring[w - 1][gq & (RS - 1)][0][0];
#pragma unroll
                        for (int q2 = 0; q2 < 8; ++q2) { mbU[q2] = rp[2 * q2]; mbS[q2] = rp[2 * q2 + 1]; }
                    }
                }
            }

            // edge handoff: shfl from lane-1 (its row-i edge, set last iter)
            float nU = __shfl_up(exU, 1);
            float nS = __shfl_up(exS, 1);
            luU = leU; luS = leS;                  // rotate: old left -> up-left
            if (t == 0)          { leU = BIGV;   leS = 1.0f; }
            else if (lane == 0)  { leU = mbU[q]; leS = mbS[q]; }
            else                 { leU = nU;     leS = nS; }

            // D for this row landed (issued 8 iterations ago)
            asm volatile("s_waitcnt vmcnt(7)" ::: "memory");
            __builtin_amdgcn_sched_barrier(0);

            if (active) {
                float4 dv = buf[q];
                float d0[4] = {dv.x, dv.y, dv.z, dv.w};
                float oU = luU, oS = luS;          // up-left pair
                float cU = leU, cS = leS;          // left pair (running)
#pragma unroll
                for (int m = 0; m < CW; ++m) {
                    float au = oU,  as_ = oS;
                    float bu = pu[m], bs = ps[m];
                    oU = pu[m]; oS = ps[m];        // next cell's up-left
                    float mn = fmin3(au, bu, cU);
                    float ea = fexp2(mn - au);
                    float eb = fexp2(mn - bu);
                    float ec = fexp2(mn - cU);
                    float sig = fmaf(cS, ec, fmaf(bs, eb, as_ * ea));
                    float un = fmaf(d0[m], LOG2E, mn);
                    pu[m] = un; ps[m] = sig;
                    cU = un; cS = sig;
                }
                exU = pu[CW - 1]; exS = ps[CW - 1];

                // producer: lane 63 of waves 0..2 -> ring (8B/row)
                if (lane == 63 && w < NWAVE - 1) {
                    const int slot = dr & 7;       // statically (q+1)&7
                    const int grp  = dr >> 3;
                    float* rp = &ring[w][grp & (RS - 1)][slot][0];
                    rp[0] = exU; rp[1] = exS;
                    if (slot == 7) {
                        asm volatile("s_waitcnt lgkmcnt(0)" ::: "memory");
                        *(volatile int*)&seqv[w] = grp;
                    }
                }
            } else if (dr < 0) {
                exU = BIGV; exS = 1.0f;            // pre-start export; keep post-end
            }

            // re-issue buf[q] for iteration j+8 (after consumption)
            {
                int rr = dr + 8; rr = rr < 0 ? 0 : (rr > N - 1 ? N - 1 : rr);
                gload4(buf[q], dbase + (size_t)rr * N);
            }

            // periodic renormalization (uniform in j; preserves values)
            if (q == 7) {
#pragma unroll
                for (int m = 0; m < CW; ++m) { pu[m] -= flog2(ps[m]); ps[m] = 1.0f; }
                exU = pu[CW - 1]; exS = 1.0f;
            }
        }
    }

    // R[N][N] = thread 255's col-1024 pair; unscale from log2 domain
    if (t == TPB - 1) out[b] = (pu[CW - 1] - flog2(ps[CW - 1])) * LN2;
}

extern "C" void kernel_launch(void* const* d_in, const int* in_sizes, int n_in,
                              void* d_out, int out_size, void* d_ws, size_t ws_size,
                              hipStream_t stream) {
    const float* D = (const float*)d_in[0];
    float* out = (float*)d_out;
    const int B = in_sizes[0] / (N * N);
    softdtw_kernel<<<B, TPB, 0, stream>>>(D, out);
}